// Round 13
// baseline (1477.989 us; speedup 1.0000x reference)
//
#include <hip/hip_runtime.h>
#include <hip/hip_cooperative_groups.h>
#include <cstdint>
#include <cstddef>

namespace cg = cooperative_groups;

#define NNODES 100000
#define NEDGES 1600000
#define DIM 128
#define NREL 8
#define NSEG (NNODES * NREL)                       // 800,000 segments
#define SCAN_BLK 2048
#define NSCAN ((NSEG + SCAN_BLK - 1) / SCAN_BLK)   // 391 scan blocks
#define NKT 36                                     // 1152 / 32 K-steps
#define A16ROW 1160                                // f16 LDS row stride (ushorts)
#define CVT4 (NNODES * DIM / 4)                    // 3,200,000 float4 groups
#define CGRID 1024                                 // co-resident coop blocks (4/CU)
#define CTHR (CGRID * 256)                         // 262,144 coop threads

// NOTE (rounds 9/10): 512-thread / 74 KB-LDS fused_layer killed the container
// twice. Envelope: <=256 threads, <=38 KB LDS for fused_layer.
// NOTE (round 12): dynamic register-array indexing (ends[cur]) in the gather
// loop doubled VALUBusy — einfo keeps the rel tag + f32 inv (8 B).

typedef float f32x4 __attribute__((ext_vector_type(4)));
typedef short short8 __attribute__((ext_vector_type(8)));
typedef _Float16 half8 __attribute__((ext_vector_type(8)));

__device__ inline float h2f(unsigned short u) {
    return (float)__builtin_bit_cast(_Float16, u);
}
__device__ inline unsigned short f2h(float f) {
    return __builtin_bit_cast(unsigned short, (_Float16)f);
}

// --------------------------------------------- cooperative prologue --------
// P0 zero cnt | P1 count+cvt | P2 scan1(+inv) | P3 scan2 | P4 scan3 |
// P5 bucket + pack W. grid.sync() (sanctioned device-wide barrier) between
// dependent phases; per-phase arithmetic identical to the proven split
// kernels of rounds 6-11.
__global__ __launch_bounds__(256) void prologue_coop(
    const int* __restrict__ src, const int* __restrict__ dst,
    const int* __restrict__ et, const float* __restrict__ x,
    unsigned short* __restrict__ xh, int* __restrict__ cnt,
    int* __restrict__ bsum, float* __restrict__ inv,
    int* __restrict__ segend, int2* __restrict__ einfo,
    const float* __restrict__ Wrel1, const float* __restrict__ Wroot1,
    const float* __restrict__ Wrel2, const float* __restrict__ Wroot2,
    unsigned short* __restrict__ Wp1, unsigned short* __restrict__ Wp2) {
    cg::grid_group grid = cg::this_grid();
    const int gtid = blockIdx.x * 256 + threadIdx.x;
    __shared__ int ws[4];

    // ---- P0: zero cnt ----
    for (int i = gtid; i < NSEG; i += CTHR) cnt[i] = 0;
    __threadfence();
    grid.sync();

    // ---- P1: count histogram + fp32->f16 cvt ----
    for (int e = gtid; e < NEDGES; e += CTHR)
        atomicAdd(&cnt[dst[e] * NREL + et[e]], 1);
    for (int i = gtid; i < CVT4; i += CTHR) {
        float4 v = *(const float4*)(x + (size_t)i * 4);
        ushort4 o = make_ushort4(f2h(v.x), f2h(v.y), f2h(v.z), f2h(v.w));
        *(ushort4*)(xh + (size_t)i * 4) = o;
    }
    __threadfence();
    grid.sync();

    // ---- P2: scan pass 1 (+inv) — blocks [0, NSCAN) ----
    if (blockIdx.x < NSCAN) {
        int base = blockIdx.x * SCAN_BLK + threadIdx.x * 8;
        int s = 0;
#pragma unroll
        for (int j = 0; j < 8; ++j) {
            int i = base + j;
            if (i < NSEG) {
                int c = cnt[i];
                s += c;
                inv[i] = 1.0f / (float)(c > 1 ? c : 1);
            }
        }
        for (int d = 1; d < 64; d <<= 1) s += __shfl_xor(s, d);
        int lane = threadIdx.x & 63, w = threadIdx.x >> 6;
        if (lane == 0) ws[w] = s;
        __syncthreads();
        if (threadIdx.x == 0) bsum[blockIdx.x] = ws[0] + ws[1] + ws[2] + ws[3];
    }
    __threadfence();
    grid.sync();

    // ---- P3: scan pass 2 — block 0, one wave ----
    if (blockIdx.x == 0 && threadIdx.x < 64) {
        int lane = threadIdx.x;
        int vals[7];
        int s = 0;
#pragma unroll
        for (int j = 0; j < 7; ++j) {
            int i = lane * 7 + j;
            vals[j] = (i < NSCAN) ? bsum[i] : 0;
            s += vals[j];
        }
        int incl = s;
        for (int d = 1; d < 64; d <<= 1) {
            int u = __shfl_up(incl, d);
            if (lane >= d) incl += u;
        }
        int base = incl - s;
#pragma unroll
        for (int j = 0; j < 7; ++j) {
            int i = lane * 7 + j;
            if (i < NSCAN) bsum[i] = base;
            base += vals[j];
        }
    }
    __threadfence();
    grid.sync();

    // ---- P4: scan pass 3 — blocks [0, NSCAN) ----
    if (blockIdx.x < NSCAN) {
        int tid = threadIdx.x;
        int base = blockIdx.x * SCAN_BLK + tid * 8;
        int v[8];
        int s = 0;
#pragma unroll
        for (int j = 0; j < 8; ++j) {
            int i = base + j;
            v[j] = (i < NSEG) ? cnt[i] : 0;
            s += v[j];
        }
        int lane = tid & 63, w = tid >> 6;
        int incl = s;
        for (int d = 1; d < 64; d <<= 1) {
            int u = __shfl_up(incl, d);
            if (lane >= d) incl += u;
        }
        __shared__ int wtot[4];
        if (lane == 63) wtot[w] = incl;
        __syncthreads();
        int wbase = 0;
#pragma unroll
        for (int k = 0; k < 4; ++k)
            if (k < w) wbase += wtot[k];
        int tbase = bsum[blockIdx.x] + wbase + (incl - s);
#pragma unroll
        for (int j = 0; j < 8; ++j) {
            int i = base + j;
            if (i < NSEG) segend[i] = tbase;   // becomes seg END after bucket
            tbase += v[j];
        }
    }
    __threadfence();
    grid.sync();

    // ---- P5: bucket (grid-stride) + pack W (disjoint outputs) ----
    for (int e = gtid; e < NEDGES; e += CTHR) {
        int seg = dst[e] * NREL + et[e];
        int p = atomicAdd(&segend[seg], 1);
        einfo[p] = make_int2(src[e] | ((seg & 7) << 20), __float_as_int(inv[seg]));
    }
    // pack: 576 virtual 64-lane units over both layers
    {
        const int lane = threadIdx.x & 63;
        for (int bb0 = gtid >> 6; bb0 < NKT * 8 * 2; bb0 += CTHR >> 6) {
            int bb = bb0;
            const float* Wrel = Wrel1;
            const float* Wroot = Wroot1;
            unsigned short* Wp = Wp1;
            if (bb >= NKT * 8) {
                bb -= NKT * 8;
                Wrel = Wrel2; Wroot = Wroot2; Wp = Wp2;
            }
            const int kt = bb >> 3, ht = bb & 7;
            const int col = ht * 16 + (lane & 15);
            const int kbase = kt * 32 + (lane >> 4) * 8;
            unsigned short vals[8];
#pragma unroll
            for (int j = 0; j < 8; ++j) {
                int k = kbase + j;
                float f = (k < 1024) ? Wrel[(size_t)k * 128 + col]
                                     : Wroot[(size_t)(k - 1024) * 128 + col];
                vals[j] = f2h(f);
            }
            unsigned short* dstp = Wp + ((size_t)bb * 64 + lane) * 8;
#pragma unroll
            for (int j = 0; j < 8; ++j) dstp[j] = vals[j];
        }
    }
}

// ---------------------------------------------------------- fused layer ----
// Round-11 proven structure (143.9 us): 16 nodes/block, 256 threads,
// fp32-accum 8-deep prefetch gather, 4 waves x 2 h-tiles MFMA.
// Head mode (ow != null): fold h2 @ out_w + sigmoid into the epilogue.
__global__ __launch_bounds__(256, 4) void fused_layer(
    const unsigned short* __restrict__ feat,   // f16 [N][128]
    const int* __restrict__ segend,
    const int2* __restrict__ einfo,
    const unsigned short* __restrict__ Wp,     // packed f16 B-frags
    const float* __restrict__ bias,
    unsigned short* __restrict__ out,          // f16 [N][128] (non-head mode)
    const float* __restrict__ ow,              // head weights or nullptr
    const float* __restrict__ ob,
    float* __restrict__ head_out) {
    __shared__ __align__(16) unsigned short A16[16 * A16ROW + 8];
    const int tid = threadIdx.x;
    const int blk = blockIdx.x;
    const int g = tid >> 4, l16 = tid & 15;

    // ---- phase 0: zero tile ----
    {
        int4* z = (int4*)A16;
        for (int i = tid; i < (16 * A16ROW) / 8; i += 256)
            z[i] = make_int4(0, 0, 0, 0);
    }
    __syncthreads();
    // root rows (disjoint 16B slices)
    *(short8*)(&A16[g * A16ROW + 1024 + l16 * 8]) =
        *(const short8*)(feat + ((size_t)blk * 16 + g) * DIM + l16 * 8);

    // ---- phase 1: pipelined gather (round-6/11 structure, fp32 accum) ----
    {
        const int n = blk * 16 + g;
        const int segbase = n * NREL;
        const int beg = (segbase == 0) ? 0 : segend[segbase - 1];
        const int end = segend[segbase + 7];
        unsigned short* Arow = &A16[g * A16ROW];

        if (beg < end) {
            const int last = end - 1;
            int2 q[8], qn[8];
            short8 v[8];
#pragma unroll
            for (int u = 0; u < 8; ++u) {
                int p = beg + u;
                q[u] = einfo[p < last ? p : last];
            }
#pragma unroll
            for (int u = 0; u < 8; ++u) {
                const int s = q[u].x & 0xFFFFF;
                v[u] = *(const short8*)(feat + (size_t)s * DIM + l16 * 8);
            }
            float acc[8] = {0.f, 0.f, 0.f, 0.f, 0.f, 0.f, 0.f, 0.f};
            int cur = ((unsigned)q[0].x) >> 20;

            for (int e = beg; e < end; e += 8) {
                // prefetch next einfo chunk
#pragma unroll
                for (int u = 0; u < 8; ++u) {
                    int p = e + 8 + u;
                    qn[u] = einfo[p < last ? p : last];
                }
                // compute current chunk
#pragma unroll
                for (int u = 0; u < 8; ++u) {
                    if (e + u < end) {
                        const int rel = ((unsigned)q[u].x) >> 20;
                        if (rel != cur) {
                            short8 o;
#pragma unroll
                            for (int j = 0; j < 8; ++j) o[j] = (short)f2h(acc[j]);
                            *(short8*)(Arow + cur * DIM + l16 * 8) = o;
#pragma unroll
                            for (int j = 0; j < 8; ++j) acc[j] = 0.f;
                            cur = rel;
                        }
                        const float sc = __int_as_float(q[u].y);
                        const short8 ve = v[u];
#pragma unroll
                        for (int j = 0; j < 8; ++j)
                            acc[j] += h2f((unsigned short)ve[j]) * sc;
                    }
                }
                // issue next chunk's feature gathers (addresses already known)
#pragma unroll
                for (int u = 0; u < 8; ++u) {
                    const int s = qn[u].x & 0xFFFFF;
                    v[u] = *(const short8*)(feat + (size_t)s * DIM + l16 * 8);
                    q[u] = qn[u];
                }
            }
            // final flush
            short8 o;
#pragma unroll
            for (int j = 0; j < 8; ++j) o[j] = (short)f2h(acc[j]);
            *(short8*)(Arow + cur * DIM + l16 * 8) = o;
        }
    }
    __syncthreads();

    // ---- phase 2: MFMA, 4 waves x 2 h-tiles ----
    const int lane = tid & 63;
    const int w = tid >> 6;                 // wave id -> h-tiles 2w, 2w+1
    const int m = lane & 15, kq = lane >> 4;
    const unsigned short* arow = &A16[m * A16ROW + kq * 8];
    f32x4 acc0 = {0.f, 0.f, 0.f, 0.f};
    f32x4 acc1 = {0.f, 0.f, 0.f, 0.f};

#pragma unroll 4
    for (int kt = 0; kt < NKT; ++kt) {
        short8 a = *(const short8*)(arow + kt * 32);
        short8 b0 = *(const short8*)(Wp + ((size_t)(kt * 8 + 2 * w) * 64 + lane) * 8);
        short8 b1 = *(const short8*)(Wp + ((size_t)(kt * 8 + 2 * w + 1) * 64 + lane) * 8);
        acc0 = __builtin_amdgcn_mfma_f32_16x16x32_f16(
            __builtin_bit_cast(half8, a), __builtin_bit_cast(half8, b0), acc0, 0, 0, 0);
        acc1 = __builtin_amdgcn_mfma_f32_16x16x32_f16(
            __builtin_bit_cast(half8, a), __builtin_bit_cast(half8, b1), acc1, 0, 0, 0);
    }

    // ---- epilogue (C/D: col=lane&15, row=(lane>>4)*4+r) ----
    const int col = lane & 15;
    const int rbase = (lane >> 4) * 4;
    const int h0 = 32 * w + col;
    const int h1 = h0 + 16;
    const float bv0 = bias[h0], bv1 = bias[h1];
    float z0[4], z1[4];
#pragma unroll
    for (int r = 0; r < 4; ++r) {
        z0[r] = fmaxf(acc0[r] + bv0, 0.f);
        z1[r] = fmaxf(acc1[r] + bv1, 0.f);
    }
    if (ow == nullptr) {
#pragma unroll
        for (int r = 0; r < 4; ++r) {
            const size_t nrow = ((size_t)blk * 16 + rbase + r) * DIM;
            out[nrow + h0] = f2h(z0[r]);
            out[nrow + h1] = f2h(z1[r]);
        }
    } else {
        // head: per-thread partial dot, LDS reduce, sigmoid (proven round 8)
        const float w0 = ow[h0], w1 = ow[h1];
        float pr[4];
#pragma unroll
        for (int r = 0; r < 4; ++r) pr[r] = z0[r] * w0 + z1[r] * w1;
        __syncthreads();                    // A16 ds_reads all complete
        float* P = (float*)A16;             // reuse LDS: [wave][node16][col16]
#pragma unroll
        for (int r = 0; r < 4; ++r)
            P[w * 256 + (rbase + r) * 16 + col] = pr[r];
        __syncthreads();
        const int gg = tid >> 4, ii = tid & 15;
        float s = P[gg * 16 + ii] + P[256 + gg * 16 + ii] +
                  P[512 + gg * 16 + ii] + P[768 + gg * 16 + ii];
        s += __shfl_xor(s, 1);
        s += __shfl_xor(s, 2);
        s += __shfl_xor(s, 4);
        s += __shfl_xor(s, 8);
        if (ii == 0)
            head_out[blk * 16 + gg] = 1.0f / (1.0f + __expf(-(s + ob[0])));
    }
}

// ---------------------------------------------------------------- launch ----
extern "C" void kernel_launch(void* const* d_in, const int* in_sizes, int n_in,
                              void* d_out, int out_size, void* d_ws, size_t ws_size,
                              hipStream_t stream) {
    const float* x      = (const float*)d_in[0];
    const int*   ei     = (const int*)d_in[1];
    const int*   et     = (const int*)d_in[2];
    const float* Wrel1  = (const float*)d_in[3];
    const float* Wroot1 = (const float*)d_in[4];
    const float* b1     = (const float*)d_in[5];
    const float* Wrel2  = (const float*)d_in[6];
    const float* Wroot2 = (const float*)d_in[7];
    const float* b2     = (const float*)d_in[8];
    const float* outw   = (const float*)d_in[9];
    const float* outb   = (const float*)d_in[10];
    const int* src = ei;
    const int* dst = ei + NEDGES;

    // workspace layout (~74 MB, 16B-aligned chunks) — round-11 layout
    char* ws = (char*)d_ws;
    int*            cnt     = (int*)(ws + 0);                    //  3,200,000
    int*            bsum    = (int*)(ws + 3200064);              //      4,096
    int*            segend  = (int*)(ws + 3204160);              //  3,200,000
    int2*           einfo   = (int2*)(ws + 6404160);             // 12,800,000
    unsigned short* xh      = (unsigned short*)(ws + 19204160);  // 25,600,000
    unsigned short* h1      = (unsigned short*)(ws + 44804160);  // 25,600,000
    unsigned short* Wp1     = (unsigned short*)(ws + 70404160);  //    294,912
    unsigned short* Wp2     = (unsigned short*)(ws + 70699072);  //    294,912
    float*          inv     = (float*)(ws + 70993984);           //  3,200,000
    // end: 74,193,984 B

    void* args[] = {(void*)&src,   (void*)&dst,    (void*)&et,    (void*)&x,
                    (void*)&xh,    (void*)&cnt,    (void*)&bsum,  (void*)&inv,
                    (void*)&segend,(void*)&einfo,  (void*)&Wrel1, (void*)&Wroot1,
                    (void*)&Wrel2, (void*)&Wroot2, (void*)&Wp1,   (void*)&Wp2};
    hipLaunchCooperativeKernel((const void*)prologue_coop, dim3(CGRID), dim3(256),
                               args, 0, stream);

    fused_layer<<<NNODES / 16, 256, 0, stream>>>(xh, segend, einfo, Wp1, b1, h1,
                                                 nullptr, nullptr, nullptr);
    fused_layer<<<NNODES / 16, 256, 0, stream>>>(h1, segend, einfo, Wp2, b2, h1,
                                                 outw, outb, (float*)d_out);
}